// Round 8
// baseline (125.984 us; speedup 1.0000x reference)
//
#include <hip/hip_runtime.h>

// ---------------------------------------------------------------------------
// GuidedAttentionL1Loss on MI355X — R7: MEASUREMENT PROBE on the R5 base.
// Three nulls in a row (R4/R5/R6 all 115±1us) and main_kernel is invisible
// (<40us, under the harness's 41us ws-poison fills that own the top-5).
// This round: repeat the seg passes NREP=3x per wave, each rep seeded by a
// runtime-zero via inline asm (blocks CSE/DCE, forces serial re-execution).
// dur_us - 115 = 2x warm-seg cost; if that is large, main_kernel surfaces in
// the top-5 WITH counters. Final rep produces the exact correct values.
// Everything else is identical to R5 (best known: wave-per-segment, 4-deep
// float4 pipeline, no barriers/LDS/atomics in hot path).
// ---------------------------------------------------------------------------

constexpr float INV_SQRT_2PI = 0.39894228040143267794f;
constexpr float NEG_HALF_LOG2E = -0.72134752044448170368f;  // -0.5*log2(e)
constexpr int L1_BLOCKS = 512;
constexpr int NREP = 3;   // PROBE: 1 cold + 2 warm repetitions of the seg work

// ws layout (bytes) — every slot written before read, no zeroing needed:
//   0:     float segpart[4096]
//   16384: float l1part[L1_BLOCKS*4]
//   24576: float nllpart[4]

__global__ __launch_bounds__(256) void main_kernel(
    const float* __restrict__ logits, const float* __restrict__ params,
    const float* __restrict__ attn, const int* __restrict__ labels,
    const int* __restrict__ lengths, int P, int Bn, int segBlocks,
    float* __restrict__ segpart, float* __restrict__ l1part,
    float* __restrict__ nllpart) {
  const int tid = threadIdx.x, lane = tid & 63, wv = tid >> 6;
  const int bid = blockIdx.x;

  if (bid < segBlocks) {
    // ---------------- segment penalty: one wave per segment, no barriers ----
    int wid = (bid << 2) + wv;
    if (wid >= Bn) return;

    // exclusive start = sum lengths[0..wid) via int4 mini-scan (L2-hot)
    int sacc = 0;
    const int4* l4 = (const int4*)lengths;
    int nq = wid >> 2;
    for (int q = lane; q < nq; q += 64) {
      int4 v = l4[q];
      sacc += (v.x + v.y) + (v.z + v.w);
    }
    if (lane < (wid & 3)) sacc += lengths[(wid & ~3) + lane];
#pragma unroll
    for (int off = 32; off; off >>= 1) sacc += __shfl_xor(sacc, off, 64);
    int start = sacc;
    int L = lengths[wid];
    int lab = labels[wid];

    const float* abase = attn + start;
    float invL = 1.0f / (float)L;
    int head = (4 - (start & 3)) & 3;   // peel to 16B alignment
    if (head > L) head = L;
    int nb = (L - head) >> 2;           // aligned float4 quads (<= 768)
    int tail = L - head - (nb << 2);
    float inv_std = (lab == 1) ? (float)L : (float)L * 0.001f;
    float dz = invL * inv_std;

    float segres = 0.f;
#pragma unroll 1
    for (int rep = 0; rep < NREP; ++rep) {
      // Opaque runtime zero: every rep's dataflow starts from a fresh value
      // the compiler cannot constant-fold -> no CSE across reps, no DCE.
      int ibias;
      asm volatile("v_mov_b32 %0, 0" : "=v"(ibias));
      const float* a = abase + ibias;
      const float4* a4 = (const float4*)(a + head);

      // ---- pass A: y-moments, 4-deep float4 pipeline ----
      float sy = 0.f, sxy = 0.f;
      auto momA = [&](const float4& v, int q) {
        float x0 = (float)(head + (q << 2) + 1) * invL;
        sy += (v.x + v.y) + (v.z + v.w);
        sxy = fmaf(x0, v.x, fmaf(x0 + invL, v.y,
              fmaf(x0 + 2.f * invL, v.z, fmaf(x0 + 3.f * invL, v.w, sxy))));
      };
      if (lane < head) {
        float y = a[lane];
        float x = (float)(lane + 1) * invL;
        sy += y; sxy = fmaf(x, y, sxy);
      }
      if (lane < tail) {
        int i = head + (nb << 2) + lane;
        float y = a[i];
        float x = (float)(i + 1) * invL;
        sy += y; sxy = fmaf(x, y, sxy);
      }
      for (int q = lane; q < nb; q += 256) {
        int q1 = q + 64, q2 = q + 128, q3 = q + 192;
        bool g1 = q1 < nb, g2 = q2 < nb, g3 = q3 < nb;
        float4 v0 = a4[q];
        float4 v1, v2, v3;
        if (g1) v1 = a4[q1];
        if (g2) v2 = a4[q2];
        if (g3) v3 = a4[q3];
        momA(v0, q);
        if (g1) momA(v1, q1);
        if (g2) momA(v2, q2);
        if (g3) momA(v3, q3);
      }
#pragma unroll
      for (int off = 32; off; off >>= 1) {
        sy  += __shfl_xor(sy, off, 64);
        sxy += __shfl_xor(sxy, off, 64);
      }
      float mean = sxy / sy;

      // ---- pass B: re-read y (L2/L3-hot); syy + e-moments ----
      float syy = 0.f, se = 0.f, sye = 0.f, see = 0.f;
      auto momB = [&](const float4& v, int q) {
        float z0 = ((float)(head + (q << 2) + 1) * invL - mean) * inv_std;
        float z1 = z0 + dz, z2 = z1 + dz, z3 = z2 + dz;
        float e0 = exp2f(z0 * z0 * NEG_HALF_LOG2E);
        float e1 = exp2f(z1 * z1 * NEG_HALF_LOG2E);
        float e2 = exp2f(z2 * z2 * NEG_HALF_LOG2E);
        float e3 = exp2f(z3 * z3 * NEG_HALF_LOG2E);
        syy = fmaf(v.x, v.x, fmaf(v.y, v.y, fmaf(v.z, v.z, fmaf(v.w, v.w, syy))));
        se += (e0 + e1) + (e2 + e3);
        sye = fmaf(v.x, e0, fmaf(v.y, e1, fmaf(v.z, e2, fmaf(v.w, e3, sye))));
        see = fmaf(e0, e0, fmaf(e1, e1, fmaf(e2, e2, fmaf(e3, e3, see))));
      };
      if (lane < head) {
        float y = a[lane];
        float z = ((float)(lane + 1) * invL - mean) * inv_std;
        float e = exp2f(z * z * NEG_HALF_LOG2E);
        syy = fmaf(y, y, syy);
        se += e; sye = fmaf(y, e, sye); see = fmaf(e, e, see);
      }
      if (lane < tail) {
        int i = head + (nb << 2) + lane;
        float y = a[i];
        float z = ((float)(i + 1) * invL - mean) * inv_std;
        float e = exp2f(z * z * NEG_HALF_LOG2E);
        syy = fmaf(y, y, syy);
        se += e; sye = fmaf(y, e, sye); see = fmaf(e, e, see);
      }
      for (int q = lane; q < nb; q += 256) {
        int q1 = q + 64, q2 = q + 128, q3 = q + 192;
        bool g1 = q1 < nb, g2 = q2 < nb, g3 = q3 < nb;
        float4 v0 = a4[q];
        float4 v1, v2, v3;
        if (g1) v1 = a4[q1];
        if (g2) v2 = a4[q2];
        if (g3) v3 = a4[q3];
        momB(v0, q);
        if (g1) momB(v1, q1);
        if (g2) momB(v2, q2);
        if (g3) momB(v3, q3);
      }
#pragma unroll
      for (int off = 32; off; off >>= 1) {
        syy += __shfl_xor(syy, off, 64);
        se  += __shfl_xor(se, off, 64);
        sye += __shfl_xor(sye, off, 64);
        see += __shfl_xor(see, off, 64);
      }
      float inv_norm = INV_SQRT_2PI * inv_std;
      float den = fmaf(inv_norm, se, 1e-6f);   // sum(rh) + 1e-6
      float c = inv_norm / den;                // rh/den scale for e-sums
      float d2 = syy - 2.0f * sye * c + see * (c * c);
      segres = d2 * invL;
      asm volatile("" : : "v"(segres));        // keep every rep's result live
    }
    if (lane == 0) segpart[wid] = segres;
  } else if (bid < segBlocks + L1_BLOCKS) {
    // ---------------- L1: per-wave partials, no barriers --------------------
    int b = bid - segBlocks;
    const float4* p4 = (const float4*)params;
    int n4 = P >> 2;
    float s = 0.f;
    for (int i = (b << 8) + tid; i < n4; i += (L1_BLOCKS << 8)) {
      float4 v = p4[i];
      s += (fabsf(v.x) + fabsf(v.y)) + (fabsf(v.z) + fabsf(v.w));
    }
    if (b == 0) {  // tail (empty when P % 4 == 0)
      for (int i = (n4 << 2) + tid; i < P; i += 256) s += fabsf(params[i]);
    }
#pragma unroll
    for (int off = 32; off; off >>= 1) s += __shfl_xor(s, off, 64);
    if (lane == 0) l1part[(b << 2) + wv] = s;
  } else {
    // ---------------- NLL: per-wave partials --------------------------------
    const float2* lg2 = (const float2*)logits;
    float s = 0.f;
    for (int r = tid; r < Bn; r += 256) {
      float2 lg = lg2[r];
      float m = fmaxf(lg.x, lg.y);
      float lse = m + logf(expf(lg.x - m) + expf(lg.y - m));
      s += lse - ((labels[r] == 1) ? lg.y : lg.x);
    }
#pragma unroll
    for (int off = 32; off; off >>= 1) s += __shfl_xor(s, off, 64);
    if (lane == 0) nllpart[wv] = s;
  }
}

// ---- finalize: one 256-thread block, f64 accumulation ----------------------
__global__ __launch_bounds__(256) void final_kernel(
    const float* __restrict__ segpart, const float* __restrict__ l1part,
    const float* __restrict__ nllpart, float* __restrict__ out, int Bn) {
  __shared__ double sA[4], sB[4], sC[4];
  int tid = threadIdx.x, lane = tid & 63, wv = tid >> 6;
  double accS = 0.0, accL = 0.0, accN = 0.0;
  const float4* s4 = (const float4*)segpart;
  for (int i = tid; i < (Bn >> 2); i += 256) {
    float4 v = s4[i];
    accS += ((double)v.x + (double)v.y) + ((double)v.z + (double)v.w);
  }
  for (int i = (Bn & ~3) + tid; i < Bn; i += 256) accS += (double)segpart[i];
  const float4* l4 = (const float4*)l1part;
  for (int i = tid; i < L1_BLOCKS; i += 256) {
    float4 v = l4[i];
    accL += ((double)v.x + (double)v.y) + ((double)v.z + (double)v.w);
  }
  if (tid < 4) accN = (double)nllpart[tid];
#pragma unroll
  for (int off = 32; off; off >>= 1) {
    accS += __shfl_down(accS, off, 64);
    accL += __shfl_down(accL, off, 64);
    accN += __shfl_down(accN, off, 64);
  }
  if (lane == 0) { sA[wv] = accS; sB[wv] = accL; sC[wv] = accN; }
  __syncthreads();
  if (tid == 0) {
    double segsum = (sA[0] + sA[1]) + (sA[2] + sA[3]);
    double l1     = (sB[0] + sB[1]) + (sB[2] + sB[3]);
    double nllsum = (sC[0] + sC[1]) + (sC[2] + sC[3]);
    double nll = nllsum / (double)Bn;
    double loss = nll + 5e-4 * l1 + 0.05 * (segsum / (double)Bn);
    out[0] = (float)loss;
    out[1] = (float)nll;
  }
}

extern "C" void kernel_launch(void* const* d_in, const int* in_sizes, int n_in,
                              void* d_out, int out_size, void* d_ws, size_t ws_size,
                              hipStream_t stream) {
  const float* logits  = (const float*)d_in[0];
  const float* params  = (const float*)d_in[1];
  const float* attn    = (const float*)d_in[2];
  const int*   labels  = (const int*)d_in[3];
  const int*   lengths = (const int*)d_in[4];
  // d_in[5] (seg_ids) unused: starts recomputed per wave from lengths.

  int Bn = in_sizes[3];
  int P  = in_sizes[1];
  int segBlocks = (Bn + 3) / 4;

  float* segpart = (float*)d_ws;
  float* l1part  = (float*)((char*)d_ws + 16384);
  float* nllpart = (float*)((char*)d_ws + 24576);

  int grid = segBlocks + L1_BLOCKS + 1;
  hipLaunchKernelGGL(main_kernel, dim3(grid), dim3(256), 0, stream,
                     logits, params, attn, labels, lengths, P, Bn, segBlocks,
                     segpart, l1part, nllpart);
  hipLaunchKernelGGL(final_kernel, dim3(1), dim3(256), 0, stream,
                     segpart, l1part, nllpart, (float*)d_out, Bn);
}

// Round 9
// 115.569 us; speedup vs baseline: 1.0901x; 1.0901x over previous
//
#include <hip/hip_runtime.h>

// ---------------------------------------------------------------------------
// GuidedAttentionL1Loss on MI355X — R8: revert R7 probe -> R5 (best: 114.3us).
// loss = nll + (ALPHA/2)*sum|params| + (BETA/2)*mean_b( sum_b (y-r)^2 / L_b )
// sum(y-r)^2 = sum y^2 - 2*sum(y*rh)/den + sum(rh^2)/den^2, den = sum(rh)+1e-6
// rh = inv_norm*e, e = exp2(-0.5*log2e*z^2); e-moments only, inv_norm folded
// into the closing algebra.
//
// ROOFLINE EVIDENCE (R7 probe, NREP=3): +2 warm seg passes cost 10-11us ->
// warm pass = 5.0-5.5us vs 5.3us HBM floor for attn (33.5MB @ 6.3TB/s).
// Timed loop is dominated by harness reset traffic (268MB ws poison @ 82%
// HBM peak = 41us + ~105MB input restore ~35us); controllable kernels are
// ~14us of which ~10us is mandatory-read floor. Remaining headroom ~4%.
// Structure: wave-per-segment, no barriers/LDS/atomics in hot path, 4-deep
// float4 pipeline, per-wave int4 mini-scan for starts (seg_ids unused).
// ---------------------------------------------------------------------------

constexpr float INV_SQRT_2PI = 0.39894228040143267794f;
constexpr float NEG_HALF_LOG2E = -0.72134752044448170368f;  // -0.5*log2(e)
constexpr int L1_BLOCKS = 512;

// ws layout (bytes) — every slot written before read, no zeroing needed:
//   0:     float segpart[4096]
//   16384: float l1part[L1_BLOCKS*4]
//   24576: float nllpart[4]

__global__ __launch_bounds__(256) void main_kernel(
    const float* __restrict__ logits, const float* __restrict__ params,
    const float* __restrict__ attn, const int* __restrict__ labels,
    const int* __restrict__ lengths, int P, int Bn, int segBlocks,
    float* __restrict__ segpart, float* __restrict__ l1part,
    float* __restrict__ nllpart) {
  const int tid = threadIdx.x, lane = tid & 63, wv = tid >> 6;
  const int bid = blockIdx.x;

  if (bid < segBlocks) {
    // ---------------- segment penalty: one wave per segment, no barriers ----
    int wid = (bid << 2) + wv;
    if (wid >= Bn) return;

    // exclusive start = sum lengths[0..wid) via int4 mini-scan (L2-hot)
    int sacc = 0;
    const int4* l4 = (const int4*)lengths;
    int nq = wid >> 2;
    for (int q = lane; q < nq; q += 64) {
      int4 v = l4[q];
      sacc += (v.x + v.y) + (v.z + v.w);
    }
    if (lane < (wid & 3)) sacc += lengths[(wid & ~3) + lane];
#pragma unroll
    for (int off = 32; off; off >>= 1) sacc += __shfl_xor(sacc, off, 64);
    int start = sacc;
    int L = lengths[wid];
    int lab = labels[wid];

    const float* a = attn + start;
    float invL = 1.0f / (float)L;
    int head = (4 - (start & 3)) & 3;   // peel to 16B alignment
    if (head > L) head = L;
    int nb = (L - head) >> 2;           // aligned float4 quads (<= 768)
    int tail = L - head - (nb << 2);
    const float4* a4 = (const float4*)(a + head);

    // ---- pass A: y-moments, 4-deep float4 pipeline ----
    float sy = 0.f, sxy = 0.f, syy = 0.f;
    auto momA = [&](const float4& v, int q) {
      float x0 = (float)(head + (q << 2) + 1) * invL;
      sy += (v.x + v.y) + (v.z + v.w);
      sxy = fmaf(x0, v.x, fmaf(x0 + invL, v.y,
            fmaf(x0 + 2.f * invL, v.z, fmaf(x0 + 3.f * invL, v.w, sxy))));
      syy = fmaf(v.x, v.x, fmaf(v.y, v.y, fmaf(v.z, v.z, fmaf(v.w, v.w, syy))));
    };
    if (lane < head) {
      float y = a[lane];
      float x = (float)(lane + 1) * invL;
      sy += y; sxy = fmaf(x, y, sxy); syy = fmaf(y, y, syy);
    }
    if (lane < tail) {
      int i = head + (nb << 2) + lane;
      float y = a[i];
      float x = (float)(i + 1) * invL;
      sy += y; sxy = fmaf(x, y, sxy); syy = fmaf(y, y, syy);
    }
    for (int q = lane; q < nb; q += 256) {
      int q1 = q + 64, q2 = q + 128, q3 = q + 192;
      bool g1 = q1 < nb, g2 = q2 < nb, g3 = q3 < nb;
      float4 v0 = a4[q];
      float4 v1, v2, v3;
      if (g1) v1 = a4[q1];
      if (g2) v2 = a4[q2];
      if (g3) v3 = a4[q3];
      momA(v0, q);
      if (g1) momA(v1, q1);
      if (g2) momA(v2, q2);
      if (g3) momA(v3, q3);
    }
#pragma unroll
    for (int off = 32; off; off >>= 1) {
      sy  += __shfl_xor(sy, off, 64);
      sxy += __shfl_xor(sxy, off, 64);
    }
    float mean = sxy / sy;
    float inv_std = (lab == 1) ? (float)L : (float)L * 0.001f;
    float dz = invL * inv_std;

    // ---- pass B: re-read y (L2/L3-hot), e-moments (inv_norm hoisted) ----
    // e = exp2(NEG_HALF_LOG2E * z^2); rh = inv_norm * e
    float se = 0.f, sye = 0.f, see = 0.f;
    auto momB = [&](const float4& v, int q) {
      float z0 = ((float)(head + (q << 2) + 1) * invL - mean) * inv_std;
      float z1 = z0 + dz, z2 = z1 + dz, z3 = z2 + dz;
      float e0 = exp2f(z0 * z0 * NEG_HALF_LOG2E);
      float e1 = exp2f(z1 * z1 * NEG_HALF_LOG2E);
      float e2 = exp2f(z2 * z2 * NEG_HALF_LOG2E);
      float e3 = exp2f(z3 * z3 * NEG_HALF_LOG2E);
      se += (e0 + e1) + (e2 + e3);
      sye = fmaf(v.x, e0, fmaf(v.y, e1, fmaf(v.z, e2, fmaf(v.w, e3, sye))));
      see = fmaf(e0, e0, fmaf(e1, e1, fmaf(e2, e2, fmaf(e3, e3, see))));
    };
    if (lane < head) {
      float y = a[lane];
      float z = ((float)(lane + 1) * invL - mean) * inv_std;
      float e = exp2f(z * z * NEG_HALF_LOG2E);
      se += e; sye = fmaf(y, e, sye); see = fmaf(e, e, see);
    }
    if (lane < tail) {
      int i = head + (nb << 2) + lane;
      float y = a[i];
      float z = ((float)(i + 1) * invL - mean) * inv_std;
      float e = exp2f(z * z * NEG_HALF_LOG2E);
      se += e; sye = fmaf(y, e, sye); see = fmaf(e, e, see);
    }
    for (int q = lane; q < nb; q += 256) {
      int q1 = q + 64, q2 = q + 128, q3 = q + 192;
      bool g1 = q1 < nb, g2 = q2 < nb, g3 = q3 < nb;
      float4 v0 = a4[q];
      float4 v1, v2, v3;
      if (g1) v1 = a4[q1];
      if (g2) v2 = a4[q2];
      if (g3) v3 = a4[q3];
      momB(v0, q);
      if (g1) momB(v1, q1);
      if (g2) momB(v2, q2);
      if (g3) momB(v3, q3);
    }
#pragma unroll
    for (int off = 32; off; off >>= 1) {
      syy += __shfl_xor(syy, off, 64);
      se  += __shfl_xor(se, off, 64);
      sye += __shfl_xor(sye, off, 64);
      see += __shfl_xor(see, off, 64);
    }
    if (lane == 0) {
      float inv_norm = INV_SQRT_2PI * inv_std;
      float den = fmaf(inv_norm, se, 1e-6f);     // sum(rh) + 1e-6
      float inv_den = 1.0f / den;
      float c = inv_norm * inv_den;               // rh/den scale for e-sums
      float d2 = syy - 2.0f * sye * c + see * (c * c);
      segpart[wid] = d2 * invL;
    }
  } else if (bid < segBlocks + L1_BLOCKS) {
    // ---------------- L1: per-wave partials, no barriers --------------------
    int b = bid - segBlocks;
    const float4* p4 = (const float4*)params;
    int n4 = P >> 2;
    float s = 0.f;
    for (int i = (b << 8) + tid; i < n4; i += (L1_BLOCKS << 8)) {
      float4 v = p4[i];
      s += (fabsf(v.x) + fabsf(v.y)) + (fabsf(v.z) + fabsf(v.w));
    }
    if (b == 0) {  // tail (empty when P % 4 == 0)
      for (int i = (n4 << 2) + tid; i < P; i += 256) s += fabsf(params[i]);
    }
#pragma unroll
    for (int off = 32; off; off >>= 1) s += __shfl_xor(s, off, 64);
    if (lane == 0) l1part[(b << 2) + wv] = s;
  } else {
    // ---------------- NLL: per-wave partials --------------------------------
    const float2* lg2 = (const float2*)logits;
    float s = 0.f;
    for (int r = tid; r < Bn; r += 256) {
      float2 lg = lg2[r];
      float m = fmaxf(lg.x, lg.y);
      float lse = m + logf(expf(lg.x - m) + expf(lg.y - m));
      s += lse - ((labels[r] == 1) ? lg.y : lg.x);
    }
#pragma unroll
    for (int off = 32; off; off >>= 1) s += __shfl_xor(s, off, 64);
    if (lane == 0) nllpart[wv] = s;
  }
}

// ---- finalize: one 256-thread block, f64 accumulation ----------------------
__global__ __launch_bounds__(256) void final_kernel(
    const float* __restrict__ segpart, const float* __restrict__ l1part,
    const float* __restrict__ nllpart, float* __restrict__ out, int Bn) {
  __shared__ double sA[4], sB[4], sC[4];
  int tid = threadIdx.x, lane = tid & 63, wv = tid >> 6;
  double accS = 0.0, accL = 0.0, accN = 0.0;
  const float4* s4 = (const float4*)segpart;
  for (int i = tid; i < (Bn >> 2); i += 256) {
    float4 v = s4[i];
    accS += ((double)v.x + (double)v.y) + ((double)v.z + (double)v.w);
  }
  for (int i = (Bn & ~3) + tid; i < Bn; i += 256) accS += (double)segpart[i];
  const float4* l4 = (const float4*)l1part;
  for (int i = tid; i < L1_BLOCKS; i += 256) {
    float4 v = l4[i];
    accL += ((double)v.x + (double)v.y) + ((double)v.z + (double)v.w);
  }
  if (tid < 4) accN = (double)nllpart[tid];
#pragma unroll
  for (int off = 32; off; off >>= 1) {
    accS += __shfl_down(accS, off, 64);
    accL += __shfl_down(accL, off, 64);
    accN += __shfl_down(accN, off, 64);
  }
  if (lane == 0) { sA[wv] = accS; sB[wv] = accL; sC[wv] = accN; }
  __syncthreads();
  if (tid == 0) {
    double segsum = (sA[0] + sA[1]) + (sA[2] + sA[3]);
    double l1     = (sB[0] + sB[1]) + (sB[2] + sB[3]);
    double nllsum = (sC[0] + sC[1]) + (sC[2] + sC[3]);
    double nll = nllsum / (double)Bn;
    double loss = nll + 5e-4 * l1 + 0.05 * (segsum / (double)Bn);
    out[0] = (float)loss;
    out[1] = (float)nll;
  }
}

extern "C" void kernel_launch(void* const* d_in, const int* in_sizes, int n_in,
                              void* d_out, int out_size, void* d_ws, size_t ws_size,
                              hipStream_t stream) {
  const float* logits  = (const float*)d_in[0];
  const float* params  = (const float*)d_in[1];
  const float* attn    = (const float*)d_in[2];
  const int*   labels  = (const int*)d_in[3];
  const int*   lengths = (const int*)d_in[4];
  // d_in[5] (seg_ids) unused: starts recomputed per wave from lengths.

  int Bn = in_sizes[3];
  int P  = in_sizes[1];
  int segBlocks = (Bn + 3) / 4;

  float* segpart = (float*)d_ws;
  float* l1part  = (float*)((char*)d_ws + 16384);
  float* nllpart = (float*)((char*)d_ws + 24576);

  int grid = segBlocks + L1_BLOCKS + 1;
  hipLaunchKernelGGL(main_kernel, dim3(grid), dim3(256), 0, stream,
                     logits, params, attn, labels, lengths, P, Bn, segBlocks,
                     segpart, l1part, nllpart);
  hipLaunchKernelGGL(final_kernel, dim3(1), dim3(256), 0, stream,
                     segpart, l1part, nllpart, (float*)d_out, Bn);
}